// Round 5
// baseline (108.182 us; speedup 1.0000x reference)
//
#include <hip/hip_runtime.h>
#include <hip/hip_fp16.h>
#include <math.h>
#include <limits.h>

#define NEGV (-1e30f)

constexpr int B = 512, T = 512, C = 128, L = 64;
constexpr int BLANK = C - 1;      // 127
constexpr float INV_LN2 = 1.44269504088896f;
constexpr float LN2 = 0.69314718055995f;
constexpr int PITCH = 66;         // halves per LDS row (33 words -> bank = lane, conflict-free)

// ---------------------------------------------------------------------------
// DPP / lane helpers
// ---------------------------------------------------------------------------
__device__ __forceinline__ float dpp_shr1_f(float x, float old) {
  int r = __builtin_amdgcn_update_dpp(__float_as_int(old), __float_as_int(x),
                                      0x138, 0xf, 0xf, false);  // wave_shr:1
  return __int_as_float(r);
}
__device__ __forceinline__ int dpp_shr1_i(int x, int old) {
  return __builtin_amdgcn_update_dpp(old, x, 0x138, 0xf, 0xf, false);
}
__device__ __forceinline__ int scan_min64(int v) {
  int t;
  t = __builtin_amdgcn_update_dpp(INT_MAX, v, 0x111, 0xf, 0xf, false); v = min(v, t);
  t = __builtin_amdgcn_update_dpp(INT_MAX, v, 0x112, 0xf, 0xf, false); v = min(v, t);
  t = __builtin_amdgcn_update_dpp(INT_MAX, v, 0x114, 0xf, 0xf, false); v = min(v, t);
  t = __builtin_amdgcn_update_dpp(INT_MAX, v, 0x118, 0xf, 0xf, false); v = min(v, t);
  t = __builtin_amdgcn_update_dpp(INT_MAX, v, 0x142, 0xa, 0xf, false); v = min(v, t);
  t = __builtin_amdgcn_update_dpp(INT_MAX, v, 0x143, 0xc, 0xf, false); v = min(v, t);
  return v;
}
__device__ __forceinline__ float scan_max64(float x) {
  const int NI = (int)0xff800000;  // -inf
  int t;
  t = __builtin_amdgcn_update_dpp(NI, __float_as_int(x), 0x111, 0xf, 0xf, false);
  x = fmaxf(x, __int_as_float(t));
  t = __builtin_amdgcn_update_dpp(NI, __float_as_int(x), 0x112, 0xf, 0xf, false);
  x = fmaxf(x, __int_as_float(t));
  t = __builtin_amdgcn_update_dpp(NI, __float_as_int(x), 0x114, 0xf, 0xf, false);
  x = fmaxf(x, __int_as_float(t));
  t = __builtin_amdgcn_update_dpp(NI, __float_as_int(x), 0x118, 0xf, 0xf, false);
  x = fmaxf(x, __int_as_float(t));
  t = __builtin_amdgcn_update_dpp(NI, __float_as_int(x), 0x142, 0xa, 0xf, false);
  x = fmaxf(x, __int_as_float(t));
  t = __builtin_amdgcn_update_dpp(NI, __float_as_int(x), 0x143, 0xc, 0xf, false);
  x = fmaxf(x, __int_as_float(t));
  return x;  // lane63 = wave max
}
__device__ __forceinline__ float scan_add64(float x) {
  int t;
  t = __builtin_amdgcn_update_dpp(0, __float_as_int(x), 0x111, 0xf, 0xf, false);
  x += __int_as_float(t);
  t = __builtin_amdgcn_update_dpp(0, __float_as_int(x), 0x112, 0xf, 0xf, false);
  x += __int_as_float(t);
  t = __builtin_amdgcn_update_dpp(0, __float_as_int(x), 0x114, 0xf, 0xf, false);
  x += __int_as_float(t);
  t = __builtin_amdgcn_update_dpp(0, __float_as_int(x), 0x118, 0xf, 0xf, false);
  x += __int_as_float(t);
  t = __builtin_amdgcn_update_dpp(0, __float_as_int(x), 0x142, 0xa, 0xf, false);
  x += __int_as_float(t);
  t = __builtin_amdgcn_update_dpp(0, __float_as_int(x), 0x143, 0xc, 0xf, false);
  x += __int_as_float(t);
  return x;  // lane63 = wave sum
}
__device__ __forceinline__ float readlane63(float x) {
  return __int_as_float(__builtin_amdgcn_readlane(__float_as_int(x), 63));
}
__device__ __forceinline__ float readlane_f(float v, int k) {
  return __int_as_float(__builtin_amdgcn_readlane(__float_as_int(v), k));
}

// ---------------------------------------------------------------------------
// K1: per-(b,t) row stats, now writing lp_lab TRANSPOSED [b][j][t] via an LDS
// transpose (conflict-free stores, coalesced 32B global writes).
// Block = 256 threads handles (b, 64 consecutive t). Grid = B * T/64.
// ---------------------------------------------------------------------------
__global__ __launch_bounds__(256) void rowstats_kernel(
    const float* __restrict__ logits, const int* __restrict__ labels,
    __half* __restrict__ lp_lab, float* __restrict__ lp_bl,
    int* __restrict__ pred) {
  __shared__ __half slp[64 * PITCH];
  int b = blockIdx.x >> 3;
  int t0 = (blockIdx.x & 7) << 6;
  int w = threadIdx.x >> 6;
  int lane = threadIdx.x & 63;
  int lab = labels[((size_t)b << 6) + lane];
  for (int i = 0; i < 16; ++i) {
    int t = t0 + w * 16 + i;
    const float* rp = logits + (size_t)(b * T + t) * C;
    float v1 = rp[lane];
    float v2 = rp[lane + 64];
    float m = readlane63(scan_max64(fmaxf(v1, v2)));
    unsigned long long b1 = __ballot(v1 == m);
    unsigned long long b2 = __ballot(v2 == m);
    int idx = b1 ? (__ffsll(b1) - 1) : (64 + __ffsll(b2) - 1);
    float s = __builtin_amdgcn_exp2f((v1 - m) * INV_LN2) +
              __builtin_amdgcn_exp2f((v2 - m) * INV_LN2);
    float l2t = __builtin_amdgcn_logf(readlane63(scan_add64(s)));
    float g1 = __shfl(v1, lab & 63);
    float g2 = __shfl(v2, lab & 63);
    float gv = (lab < 64) ? g1 : g2;
    slp[lane * PITCH + (t - t0)] = __float2half((gv - m) * INV_LN2 - l2t);
    if (lane == 63) lp_bl[b * T + t] = (v2 - m) * INV_LN2 - l2t;
    if (lane == 0) pred[b * T + t] = idx;
  }
  __syncthreads();
  // writeout: thread k -> (j = k/4, quarter q = k%4): 32B of row j
  int j = threadIdx.x >> 2, q = threadIdx.x & 3;
  unsigned wbuf[8];
#pragma unroll
  for (int wd = 0; wd < 8; ++wd)
    wbuf[wd] = ((const unsigned*)slp)[j * (PITCH / 2) + q * 8 + wd];
  uint4 o0 = make_uint4(wbuf[0], wbuf[1], wbuf[2], wbuf[3]);
  uint4 o1 = make_uint4(wbuf[4], wbuf[5], wbuf[6], wbuf[7]);
  uint4* dst = (uint4*)(lp_lab + ((size_t)((b << 6) + j)) * T + t0 + q * 16);
  dst[0] = o0;
  dst[1] = o1;
}

// ---------------------------------------------------------------------------
// CTC alpha step, log2 domain. Lane j holds states {2j, 2j+1}; aL = state 128.
// ---------------------------------------------------------------------------
__device__ __forceinline__ float lse2_2(float a, float b) {
  float m = fmaxf(a, b);
  float d = fminf(a, b) - m;
  return m + __builtin_amdgcn_logf(1.0f + __builtin_amdgcn_exp2f(d));
}
__device__ __forceinline__ void ctc_step(float lpl, float lpb, bool skip_ok,
                                         bool needL,
                                         float& aE, float& aO, float& aL) {
  float pO = dpp_shr1_f(aO, NEGV);   // alpha[2j-1]
  float pE = dpp_shr1_f(aE, NEGV);   // alpha[2j-2]
  float a3 = skip_ok ? pE : NEGV;
  float nE = lse2_2(aE, pO) + lpb;   // even state 2j (blank)
  float mO = fmaxf(fmaxf(aO, aE), a3);
  float sO = __builtin_amdgcn_exp2f(aO - mO) + __builtin_amdgcn_exp2f(aE - mO)
           + __builtin_amdgcn_exp2f(a3 - mO);
  float nO = mO + __builtin_amdgcn_logf(sO) + lpl;  // odd state 2j+1
  float nL = lse2_2(aL, aO) + lpb;                  // state 128 (tail blank)
  aL = needL ? nL : aL;
  aE = nE; aO = nO;
}

// extract half #k (0..63) from an 8x uint4 register buffer (k constant)
__device__ __forceinline__ float get_h(const uint4 (&buf)[8], int k) {
  uint4 v = buf[k >> 3];
  int c2 = (k >> 1) & 3;
  unsigned comp = (c2 == 0) ? v.x : (c2 == 1) ? v.y : (c2 == 2) ? v.z : v.w;
  unsigned hs = (k & 1) ? (comp >> 16) : (comp & 0xffffu);
  unsigned short us = (unsigned short)hs;
  __half h;
  __builtin_memcpy(&h, &us, 2);
  return __half2float(h);
}

// predicated edit-distance step (keep is wave-uniform)
__device__ __forceinline__ void edit_step(int cc, int lab, int lane,
                                          int& row, int& i, int& prevc) {
  int rowm1 = dpp_shr1_i(row, i);    // row[col-1]; lane0 -> row[0] = i
  int v = min(rowm1 + (cc != lab), row + 1) - (lane + 1);
  v = scan_min64(v);
  int nrow = (lane + 1) + min(v, i + 1);
  bool keep = (cc != BLANK) && (cc != prevc);
  row = keep ? nrow : row;
  i += keep ? 1 : 0;
  prevc = cc;
}

// ---------------------------------------------------------------------------
// K2 fused: blocks [0,B) = CTC; blocks [B,2B) = edit distance.
// 64-step superchunks: per superchunk the whole operand set is 8 uint4 loads
// (lane-contiguous transposed lp_lab) + 1 coalesced dword (lp_bl / pred,
// broadcast per-step via v_readlane). Double-buffered A/B.
// ---------------------------------------------------------------------------
__global__ __launch_bounds__(64, 1) void dp_kernel(
    const __half* __restrict__ lp_lab, const float* __restrict__ lp_bl,
    const int* __restrict__ pred, const int* __restrict__ labels,
    const int* __restrict__ label_len, const int* __restrict__ logit_len,
    float* __restrict__ loss_b, float* __restrict__ ler_b) {
  int lane = threadIdx.x;
  if (blockIdx.x < (unsigned)B) {
    // ---------------- CTC path ----------------
    int b = blockIdx.x;
    int tl = logit_len[b];
    int ll = label_len[b];
    bool needL = (ll == L);
    int lab = labels[((size_t)b << 6) + lane];
    int labp = __shfl_up(lab, 1);
    bool skip_ok = (lane > 0) && (lab != labp);
    const __half* lpl_h = lp_lab + ((size_t)((b << 6) + lane)) * T;
    const float* lpbb = lp_bl + (size_t)b * T;
    float aE, aO, aL = NEGV;

    if (tl == T) {
      const uint4* lpl4 = (const uint4*)lpl_h;
      uint4 Abuf[8], Bbuf[8];
      float vbA, vbB;
#pragma unroll
      for (int r = 0; r < 8; ++r) Abuf[r] = lpl4[r];
      vbA = lpbb[lane];
#pragma unroll
      for (int r = 0; r < 8; ++r) Bbuf[r] = lpl4[8 + r];
      vbB = lpbb[64 + lane];
      __builtin_amdgcn_sched_barrier(0);
      {
        float lpb0 = readlane_f(vbA, 0);
        float lpl0 = get_h(Abuf, 0);
        aE = (lane == 0) ? lpb0 : NEGV;   // s=0: blank at t=0
        aO = (lane == 0) ? lpl0 : NEGV;   // s=1: labels[0] at t=0
      }
#pragma unroll
      for (int k = 1; k < 64; ++k)
        ctc_step(get_h(Abuf, k), readlane_f(vbA, k), skip_ok, needL, aE, aO, aL);
#pragma unroll 1
      for (int g = 1; g < 8; g += 2) {
        if (g + 1 < 8) {
#pragma unroll
          for (int r = 0; r < 8; ++r) Abuf[r] = lpl4[(g + 1) * 8 + r];
          vbA = lpbb[(g + 1) * 64 + lane];
        }
        __builtin_amdgcn_sched_barrier(0);
#pragma unroll
        for (int k = 0; k < 64; ++k)
          ctc_step(get_h(Bbuf, k), readlane_f(vbB, k), skip_ok, needL, aE, aO, aL);
        if (g + 2 < 8) {
#pragma unroll
          for (int r = 0; r < 8; ++r) Bbuf[r] = lpl4[(g + 2) * 8 + r];
          vbB = lpbb[(g + 2) * 64 + lane];
        }
        __builtin_amdgcn_sched_barrier(0);
        if (g + 1 < 8) {
#pragma unroll
          for (int k = 0; k < 64; ++k)
            ctc_step(get_h(Abuf, k), readlane_f(vbA, k), skip_ok, needL, aE, aO, aL);
        }
      }
    } else {
      // general fallback (not exercised by this input shape)
      aE = (lane == 0) ? lpbb[0] : NEGV;
      aO = (lane == 0) ? __half2float(lpl_h[0]) : NEGV;
      for (int t = 1; t < tl; ++t)
        ctc_step(__half2float(lpl_h[t]), lpbb[t], skip_ok, needL, aE, aO, aL);
    }
    float e1 = needL ? __shfl(aL, 63) : __shfl(aE, ll);  // alpha[2*ll]
    float e2 = __shfl(aO, ll - 1);                       // alpha[2*ll-1]
    if (lane == 0) {
      float m = fmaxf(e1, e2);
      float r = m + __builtin_amdgcn_logf(__builtin_amdgcn_exp2f(e1 - m) +
                                          __builtin_amdgcn_exp2f(e2 - m));
      loss_b[b] = -r * LN2;
    }
  } else {
    // ---------------- edit-distance path ----------------
    int b = blockIdx.x - B;
    int tl = logit_len[b];
    int ll = label_len[b];
    int lab = labels[((size_t)b << 6) + lane];  // lane j owns DP column j+1
    const int* pb = pred + (size_t)b * T;
    int row = lane + 1;   // row0[col] = col
    int i = 0;            // kept chars consumed (= row[0])
    int prevc = -1;

    if (tl == T) {
      int pA = pb[lane];
      int pB = pb[64 + lane];
      __builtin_amdgcn_sched_barrier(0);
#pragma unroll
      for (int k = 0; k < 64; ++k)
        edit_step(__builtin_amdgcn_readlane(pA, k), lab, lane, row, i, prevc);
#pragma unroll 1
      for (int g = 1; g < 8; g += 2) {
        if (g + 1 < 8) pA = pb[(g + 1) * 64 + lane];
        __builtin_amdgcn_sched_barrier(0);
#pragma unroll
        for (int k = 0; k < 64; ++k)
          edit_step(__builtin_amdgcn_readlane(pB, k), lab, lane, row, i, prevc);
        if (g + 2 < 8) pB = pb[(g + 2) * 64 + lane];
        __builtin_amdgcn_sched_barrier(0);
        if (g + 1 < 8) {
#pragma unroll
          for (int k = 0; k < 64; ++k)
            edit_step(__builtin_amdgcn_readlane(pA, k), lab, lane, row, i, prevc);
        }
      }
    } else {
      for (int t = 0; t < tl; ++t)
        edit_step(pb[t], lab, lane, row, i, prevc);
    }
    if (lane == ll - 1) ler_b[b] = (float)row / (float)ll;
  }
}

// ---------------------------------------------------------------------------
// K3: deterministic final mean over B for loss and ler.
// ---------------------------------------------------------------------------
__global__ __launch_bounds__(512) void reduce_kernel(
    const float* __restrict__ loss_b, const float* __restrict__ ler_b,
    float* __restrict__ out) {
  __shared__ float sl[512];
  __shared__ float sr[512];
  int tid = threadIdx.x;
  sl[tid] = loss_b[tid];
  sr[tid] = ler_b[tid];
  __syncthreads();
  for (int off = 256; off; off >>= 1) {
    if (tid < off) { sl[tid] += sl[tid + off]; sr[tid] += sr[tid + off]; }
    __syncthreads();
  }
  if (tid == 0) {
    out[0] = sl[0] / (float)B;
    out[1] = sr[0] / (float)B;
  }
}

extern "C" void kernel_launch(void* const* d_in, const int* in_sizes, int n_in,
                              void* d_out, int out_size, void* d_ws, size_t ws_size,
                              hipStream_t stream) {
  const int*   labels    = (const int*)d_in[0];
  const float* logits    = (const float*)d_in[1];
  const int*   label_len = (const int*)d_in[2];
  const int*   logit_len = (const int*)d_in[3];
  float* out = (float*)d_out;

  char* ws = (char*)d_ws;
  __half* lp_lab = (__half*)ws;                                  // B*64*T f16 = 32 MB (transposed)
  float*  lp_bl  = (float*)(ws + (size_t)B * T * 64 * 2);        // B*T f32   =  1 MB
  int*    pred   = (int*)(ws + (size_t)B * T * 64 * 2 + (size_t)B * T * 4);
  float*  loss_b = (float*)(ws + (size_t)B * T * 64 * 2 + (size_t)2 * B * T * 4);
  float*  ler_b  = loss_b + B;

  rowstats_kernel<<<B * (T / 64), 256, 0, stream>>>(logits, labels, lp_lab, lp_bl, pred);
  dp_kernel<<<2 * B, 64, 0, stream>>>(lp_lab, lp_bl, pred, labels, label_len,
                                      logit_len, loss_b, ler_b);
  reduce_kernel<<<1, 512, 0, stream>>>(loss_b, ler_b, out);
}